// Round 1
// baseline (255.889 us; speedup 1.0000x reference)
//
#include <hip/hip_runtime.h>
#include <hip/hip_bf16.h>

// RNN wavefunction log-prob: N=128 steps, B=8192, H=128, D=2 (one-hot).
// R8: LDS-pipe-bound theory. 256 threads (4 waves); wave owns 32 hidden
// rows (2 M-tiles) -> each ds_read_b128 of h feeds 2x MFMA, halving the
// per-CU LDS broadcast traffic. Biases + dense head live in registers
// (sBias/sFwd LDS dropped). ~210 VGPR, launch_bounds(256,2).

#define NSTEP 128
#define BTOT  8192
#define HID   128
#define MB    16
#define NBLK  (BTOT / MB)   // 512
#define NTHR  256

typedef __attribute__((ext_vector_type(8))) short bf16x8;
typedef __attribute__((ext_vector_type(4))) float f32x4;
typedef __attribute__((ext_vector_type(2))) float f32x2;
typedef __attribute__((ext_vector_type(2))) unsigned uint32x2;

__device__ __forceinline__ short f2bf(float v) {
    unsigned u = __builtin_bit_cast(unsigned, v);
    u += 0x7FFFu + ((u >> 16) & 1u);
    return (short)(u >> 16);
}
// two f32 -> packed bf16x2
__device__ __forceinline__ unsigned cvt2bf(float a, float b) {
    __hip_bfloat162 h2 = __float22bfloat162_rn(make_float2(a, b));
    unsigned u; __builtin_memcpy(&u, &h2, sizeof(u));
    return u;
}
// tanh pair, independent rcp (shorter dep chain than shared-rcp trick)
__device__ __forceinline__ f32x2 tanh2(f32x2 x) {
    f32x2 z = x * 2.885390081777927f;            // 2x*log2(e)
    float r0 = __builtin_amdgcn_rcpf(__builtin_exp2f(z.x) + 1.0f);
    float r1 = __builtin_amdgcn_rcpf(__builtin_exp2f(z.y) + 1.0f);
    f32x2 r = {r0, r1};
    return r * -2.0f + 1.0f;                     // 1 - 2/(e^2x+1)
}

__global__ __launch_bounds__(NTHR, 2) void rnn_wf_kernel(
    const float* __restrict__ samples,  // (128, 8192, 2)
    const float* __restrict__ Wih0,     // (128, 2)
    const float* __restrict__ bih0,     // (128,)
    const float* __restrict__ Whh0,     // (128, 128)
    const float* __restrict__ bhh0,     // (128,)
    const float* __restrict__ Wih1,     // (128, 128)
    const float* __restrict__ bih1,     // (128,)
    const float* __restrict__ Whh1,     // (128, 128)
    const float* __restrict__ bhh1,     // (128,)
    const float* __restrict__ Wd,       // (2, 128)
    const float* __restrict__ bd,       // (2,)
    float* __restrict__ out)            // (1, 8192)
{
    __shared__ short sH0[2][MB * HID];
    __shared__ short sH1[2][MB * HID];
    __shared__ unsigned sMask[NSTEP];
    __shared__ float sLd[NSTEP * 17];            // logit diffs [t*17 + s]

    const int tid  = threadIdx.x;
    const int b0   = blockIdx.x * MB;
    const int w    = tid >> 6;          // wave 0..3, owns n in [32w, 32w+32)
    const int lane = tid & 63;
    const int q    = lane >> 4;
    const int c    = lane & 15;

    // ---- decode f32 one-hot samples -> per-step 16-bit masks ----
    if (tid < NSTEP) {
        unsigned msk = 0;
        #pragma unroll
        for (int m = 0; m < MB; ++m) {
            float e1 = samples[((size_t)tid * BTOT + b0 + m) * 2 + 1];
            if (e1 > 0.5f) msk |= (1u << m);
        }
        sMask[tid] = msk;
    }

    // ---- weight A-fragments in registers: lane holds W[32w+16t+c][kb*32+q*8 ..+8]
    bf16x8 fhh0[2][4], fih1[2][4], fhh1[2][4], fw[4];
    {
        auto ldf = [](const float* p) {
            f32x4 l0 = *reinterpret_cast<const f32x4*>(p);
            f32x4 l1 = *reinterpret_cast<const f32x4*>(p + 4);
            bf16x8 v;
            v[0]=f2bf(l0[0]); v[1]=f2bf(l0[1]); v[2]=f2bf(l0[2]); v[3]=f2bf(l0[3]);
            v[4]=f2bf(l1[0]); v[5]=f2bf(l1[1]); v[6]=f2bf(l1[2]); v[7]=f2bf(l1[3]);
            return v;
        };
        #pragma unroll
        for (int t = 0; t < 2; ++t) {
            const int nn = w * 32 + t * 16 + c;
            #pragma unroll
            for (int kb = 0; kb < 4; ++kb) {
                const int off = nn * HID + kb * 32 + q * 8;
                fhh0[t][kb] = ldf(Whh0 + off);
                fih1[t][kb] = ldf(Wih1 + off);
                fhh1[t][kb] = ldf(Whh1 + off);
            }
        }
        #pragma unroll
        for (int kb = 0; kb < 4; ++kb) {
            bf16x8 v;
            #pragma unroll
            for (int j = 0; j < 8; ++j)
                v[j] = (c < 2) ? f2bf(Wd[c * HID + kb * 32 + q * 8 + j]) : (short)0;
            fw[kb] = v;
        }
    }

    // ---- biases in registers (per M-tile f32x4 for acc rows 4q..4q+3) ----
    f32x4 bWA[2], bWB[2], bB1[2], bP[2];
    #pragma unroll
    for (int t = 0; t < 2; ++t) {
        const int n0 = w * 32 + t * 16 + q * 4;
        f32x4 vi = *reinterpret_cast<const f32x4*>(&bih0[n0]);
        f32x4 vh = *reinterpret_cast<const f32x4*>(&bhh0[n0]);
        f32x4 bb = vi + vh;
        f32x4 wA = *reinterpret_cast<const f32x4*>(&Wih0[n0 * 2]);      // rows n0,n0+1
        f32x4 wB = *reinterpret_cast<const f32x4*>(&Wih0[n0 * 2 + 4]);  // rows n0+2,n0+3
        bP[t]  = bb;
        bWA[t] = bb + (f32x4){wA[0], wA[2], wB[0], wB[2]};  // + Wih0[:,0]
        bWB[t] = bb + (f32x4){wA[1], wA[3], wB[1], wB[3]};  // + Wih0[:,1]
        f32x4 v1 = *reinterpret_cast<const f32x4*>(&bih1[n0]);
        f32x4 v2 = *reinterpret_cast<const f32x4*>(&bhh1[n0]);
        bB1[t] = v1 + v2;
    }
    const float bd0 = bd[0], bd1 = bd[1];

    // ---- t-invariant LDS indices (same XOR swizzle family as before) ----
    int ra[4];
    #pragma unroll
    for (int kb = 0; kb < 4; ++kb)
        ra[kb] = c * HID + (((kb * 4 + q) ^ c) << 3);
    // write: h'[m=c][n = 32w + 16t + 4q + r]; 8-block = 4w+2t+(q>>1), half q&1
    int wa[2];
    #pragma unroll
    for (int t = 0; t < 2; ++t)
        wa[t] = c * HID + (((4 * w + 2 * t + (q >> 1)) ^ c) << 3) + ((q & 1) << 2);

    bool bmPrev = false;

    auto storeT = [&](short* buf, int t, const f32x4& a) {
        f32x2 t0 = tanh2((f32x2){a[0], a[1]});
        f32x2 t1 = tanh2((f32x2){a[2], a[3]});
        uint32x2 v = {cvt2bf(t0.x, t0.y), cvt2bf(t1.x, t1.y)};
        *reinterpret_cast<uint32x2*>(&buf[wa[t]]) = v;
    };

    __syncthreads();                 // sMask published

    // ---- i = 0: h0(0) = tanh(b0) ----
    storeT(sH0[1], 0, bP[0]);
    storeT(sH0[1], 1, bP[1]);
    __syncthreads();

    // ---- i = 1: h0(1), h1(0) ----
    {
        const bool bmIn = (sMask[0] >> c) & 1u;
        bf16x8 f0[4];
        #pragma unroll
        for (int kb = 0; kb < 4; ++kb)
            f0[kb] = *reinterpret_cast<const bf16x8*>(&sH0[1][ra[kb]]);
        f32x4 a0[2], a1[2];
        #pragma unroll
        for (int t = 0; t < 2; ++t) { a0[t] = bmIn ? bWB[t] : bWA[t]; a1[t] = bB1[t]; }
        #pragma unroll
        for (int kb = 0; kb < 4; ++kb) {
            #pragma unroll
            for (int t = 0; t < 2; ++t) {
                a0[t] = __builtin_amdgcn_mfma_f32_16x16x32_bf16(fhh0[t][kb], f0[kb], a0[t], 0, 0, 0);
                a1[t] = __builtin_amdgcn_mfma_f32_16x16x32_bf16(fih1[t][kb], f0[kb], a1[t], 0, 0, 0);
            }
        }
        #pragma unroll
        for (int t = 0; t < 2; ++t) { storeT(sH0[0], t, a0[t]); storeT(sH1[0], t, a1[t]); }
        bmPrev = bmIn;
        __syncthreads();
    }

    // ---- main: i = 2..127, one barrier per iteration ----
    auto stepMain = [&](int i, const short* r0, const short* r1,
                        short* w0b, short* w1b) {
        const bool bmIn = (sMask[i - 1] >> c) & 1u;
        bf16x8 f0[4], f1[4];
        #pragma unroll
        for (int kb = 0; kb < 4; ++kb) {
            f0[kb] = *reinterpret_cast<const bf16x8*>(&r0[ra[kb]]);
            f1[kb] = *reinterpret_cast<const bf16x8*>(&r1[ra[kb]]);
        }
        f32x4 a0[2], a1[2];
        #pragma unroll
        for (int t = 0; t < 2; ++t) { a0[t] = bmIn ? bWB[t] : bWA[t]; a1[t] = bB1[t]; }
        #pragma unroll
        for (int kb = 0; kb < 4; ++kb) {
            #pragma unroll
            for (int t = 0; t < 2; ++t) {
                a0[t] = __builtin_amdgcn_mfma_f32_16x16x32_bf16(fhh0[t][kb], f0[kb], a0[t], 0, 0, 0);
                a1[t] = __builtin_amdgcn_mfma_f32_16x16x32_bf16(fhh1[t][kb], f1[kb], a1[t], 0, 0, 0);
            }
        }
        #pragma unroll
        for (int kb = 0; kb < 4; ++kb) {
            #pragma unroll
            for (int t = 0; t < 2; ++t)
                a1[t] = __builtin_amdgcn_mfma_f32_16x16x32_bf16(fih1[t][kb], f0[kb], a1[t], 0, 0, 0);
        }
        if (w == (i & 3)) {   // rotate logits duty across the 4 waves
            f32x4 aL = {bd0, bd1, 0.f, 0.f};
            #pragma unroll
            for (int kb = 0; kb < 4; ++kb)
                aL = __builtin_amdgcn_mfma_f32_16x16x32_bf16(fw[kb], f1[kb], aL, 0, 0, 0);
            if (q == 0)
                sLd[(i - 2) * 17 + c] = bmPrev ? (aL[0] - aL[1]) : (aL[1] - aL[0]);
        }
        bmPrev = bmIn;
        #pragma unroll
        for (int t = 0; t < 2; ++t) { storeT(w0b, t, a0[t]); storeT(w1b, t, a1[t]); }
        __syncthreads();
    };

    for (int i = 2; i < NSTEP; i += 2) {
        stepMain(i,     sH0[0], sH1[0], sH0[1], sH1[1]);
        stepMain(i + 1, sH0[1], sH1[1], sH0[0], sH1[0]);
    }

    // ---- i = 128: h1(127), logits(126) ----
    {
        bf16x8 f0[4], f1[4];
        #pragma unroll
        for (int kb = 0; kb < 4; ++kb) {
            f0[kb] = *reinterpret_cast<const bf16x8*>(&sH0[0][ra[kb]]);  // h0(127)
            f1[kb] = *reinterpret_cast<const bf16x8*>(&sH1[0][ra[kb]]);  // h1(126)
        }
        f32x4 a1[2];
        #pragma unroll
        for (int t = 0; t < 2; ++t) a1[t] = bB1[t];
        #pragma unroll
        for (int kb = 0; kb < 4; ++kb) {
            #pragma unroll
            for (int t = 0; t < 2; ++t)
                a1[t] = __builtin_amdgcn_mfma_f32_16x16x32_bf16(fhh1[t][kb], f1[kb], a1[t], 0, 0, 0);
        }
        #pragma unroll
        for (int kb = 0; kb < 4; ++kb) {
            #pragma unroll
            for (int t = 0; t < 2; ++t)
                a1[t] = __builtin_amdgcn_mfma_f32_16x16x32_bf16(fih1[t][kb], f0[kb], a1[t], 0, 0, 0);
        }
        if (w == 0) {         // 128 & 3 == 0, keeps the rotation
            f32x4 aL = {bd0, bd1, 0.f, 0.f};
            #pragma unroll
            for (int kb = 0; kb < 4; ++kb)
                aL = __builtin_amdgcn_mfma_f32_16x16x32_bf16(fw[kb], f1[kb], aL, 0, 0, 0);
            if (q == 0)
                sLd[126 * 17 + c] = bmPrev ? (aL[0] - aL[1]) : (aL[1] - aL[0]);
        }
        #pragma unroll
        for (int t = 0; t < 2; ++t) storeT(sH1[1], t, a1[t]);
        __syncthreads();
    }
    // ---- i = 129: logits(127), wave 1 ----
    if (w == 1) {
        f32x4 aL = {bd0, bd1, 0.f, 0.f};
        #pragma unroll
        for (int kb = 0; kb < 4; ++kb) {
            bf16x8 f1 = *reinterpret_cast<const bf16x8*>(&sH1[1][ra[kb]]);
            aL = __builtin_amdgcn_mfma_f32_16x16x32_bf16(fw[kb], f1, aL, 0, 0, 0);
        }
        if (q == 0) {
            const bool bit = (sMask[NSTEP - 1] >> c) & 1u;
            sLd[127 * 17 + c] = bit ? (aL[0] - aL[1]) : (aL[1] - aL[0]);
        }
    }
    __syncthreads();

    // ---- final pass: lp(s) = sum_t -log(1 + exp(diff_t)) ----
    {
        const int s = tid >> 4;       // sample 0..15
        const int k = tid & 15;       // step sub-index
        float acc = 0.0f;
        #pragma unroll
        for (int j = 0; j < 8; ++j) {
            const float x = sLd[(j * 16 + k) * 17 + s];
            const float ed = __builtin_exp2f(x * 1.4426950408889634f);
            acc -= 0.6931471805599453f * __builtin_log2f(1.0f + ed);
        }
        #pragma unroll
        for (int off = 1; off < 16; off <<= 1)
            acc += __shfl_xor(acc, off, 64);
        if (k == 0)
            out[b0 + s] = acc;
    }
}

extern "C" void kernel_launch(void* const* d_in, const int* in_sizes, int n_in,
                              void* d_out, int out_size, void* d_ws, size_t ws_size,
                              hipStream_t stream) {
    rnn_wf_kernel<<<NBLK, NTHR, 0, stream>>>(
        (const float*)d_in[0],  // samples
        (const float*)d_in[1],  // W_ih0
        (const float*)d_in[2],  // b_ih0
        (const float*)d_in[3],  // W_hh0
        (const float*)d_in[4],  // b_hh0
        (const float*)d_in[5],  // W_ih1
        (const float*)d_in[6],  // b_ih1
        (const float*)d_in[7],  // W_hh1
        (const float*)d_in[8],  // b_hh1
        (const float*)d_in[9],  // W_dense
        (const float*)d_in[10], // b_dense
        (float*)d_out);
}